// Round 6
// baseline (330.486 us; speedup 1.0000x reference)
//
#include <hip/hip_runtime.h>
#include <hip/hip_bf16.h>

// SpatialMamba — LITERAL reference port, f32 OUTPUT experiment.
// One block per (direction, sequence); every phase recomputed locally in LDS.
// The 4 directions atomicAdd their projected outputs directly into d_out (f32),
// which is memset to 0 at the start of kernel_launch.
// ONLY change vs round 5: output dtype/path (bf16+ws-acc -> direct f32).

constexpr int BN = 4, SL = 48;
constexpr int NPIX = BN * SL * SL;     // 9216
constexpr int L = SL;
constexpr int NSEQ = BN * SL;          // 192 sequences per direction
constexpr int NBLK = 4 * NSEQ;         // 768

__global__ __launch_bounds__(256) void k_seq(
    const float* __restrict__ x,      // [NPIX][32]
    const float* __restrict__ Win,    // [128][32]
    const float* __restrict__ convw,  // [64][4]
    const float* __restrict__ convb,  // [64]
    const float* __restrict__ Wx,     // [192][64]
    const float* __restrict__ Wdt,    // [64][64]
    const float* __restrict__ bdt,    // [64]
    const float* __restrict__ Alog,   // [64][64]
    const float* __restrict__ Dv,     // [64]
    const float* __restrict__ Wout,   // [32][64]
    float* __restrict__ out) {        // [NPIX][32] f32, pre-zeroed
  __shared__ float xt[L][32];    // 6 KB  input tile
  __shared__ float dl[L][64];    // 12 KB raw in-proj, later delta
  __shared__ float gz[L][64];    // 12 KB silu(z)
  __shared__ float xs[L][64];    // 12 KB conv+silu
  __shared__ float sp[L][192];   // 36 KB {d_in,Bp,Cp}; d_in cols reused for y

  int tid = threadIdx.x;
  int bid = blockIdx.x;
  int dir = bid / NSEQ;
  int seq = bid % NSEQ;
  int b = seq / SL, q = seq % SL;
  int pbase, pstride;
  if (dir == 0)      { pbase = (b * SL) * SL + q;           pstride = SL;  }  // seq along H fwd, q=w
  else if (dir == 1) { pbase = (b * SL + SL - 1) * SL + q;  pstride = -SL; }  // H bwd
  else if (dir == 2) { pbase = (b * SL + q) * SL;           pstride = 1;   }  // seq along W fwd, q=h
  else               { pbase = (b * SL + q) * SL + SL - 1;  pstride = -1;  }  // W bwd

  // P0: stage x tile
  for (int e = tid; e < L * 32; e += 256) {
    int t = e >> 5, c = e & 31;
    xt[t][c] = x[(pbase + t * pstride) * 32 + c];
  }
  __syncthreads();

  // P1: in-projection. dl[t][d] = x.Win_row(d);  gz[t][d] = silu(x.Win_row(64+d))
  for (int e = tid; e < L * 64; e += 256) {
    int t = e >> 6, d = e & 63;
    const float4* wa = reinterpret_cast<const float4*>(Win + d * 32);
    const float4* wb = reinterpret_cast<const float4*>(Win + (64 + d) * 32);
    const float* xv = xt[t];
    float s0 = 0.f, s1 = 0.f;
    #pragma unroll
    for (int i = 0; i < 8; ++i) {
      float4 a = wa[i], bw = wb[i];
      const float* xp = xv + i * 4;
      s0 += a.x * xp[0] + a.y * xp[1] + a.z * xp[2] + a.w * xp[3];
      s1 += bw.x * xp[0] + bw.y * xp[1] + bw.z * xp[2] + bw.w * xp[3];
    }
    dl[t][d] = s0;
    gz[t][d] = s1 / (1.f + __expf(-s1));
  }
  __syncthreads();

  // P2: causal depthwise conv k=4 (left zero-pad) + silu
  for (int e = tid; e < L * 64; e += 256) {
    int t = e >> 6, d = e & 63;
    float4 cw = reinterpret_cast<const float4*>(convw)[d];   // w[0..3]
    float s = convb[d] + dl[t][d] * cw.w;
    if (t >= 1) s += dl[t - 1][d] * cw.z;
    if (t >= 2) s += dl[t - 2][d] * cw.y;
    if (t >= 3) s += dl[t - 3][d] * cw.x;
    xs[t][d] = s / (1.f + __expf(-s));
  }
  __syncthreads();

  // P3: sp[t][r] = xs[t] . Wx_row(r), r = 0..191  (d_in | Bp | Cp)
  for (int e = tid; e < L * 192; e += 256) {
    int t = e / 192, r = e % 192;
    const float4* w4 = reinterpret_cast<const float4*>(Wx + r * 64);
    const float* xv = xs[t];
    float s = 0.f;
    #pragma unroll
    for (int i = 0; i < 16; ++i) {
      float4 w = w4[i];
      const float* xp = xv + i * 4;
      s += w.x * xp[0] + w.y * xp[1] + w.z * xp[2] + w.w * xp[3];
    }
    sp[t][r] = s;
  }
  __syncthreads();

  // P4: delta[t][i] = softplus(d_in[t] . Wdt_row(i) + bdt[i])  (overwrites dl)
  for (int e = tid; e < L * 64; e += 256) {
    int t = e >> 6, i = e & 63;
    const float4* w4 = reinterpret_cast<const float4*>(Wdt + i * 64);
    const float* dv = sp[t];                       // d_in = sp[t][0..63]
    float s = bdt[i];
    #pragma unroll
    for (int k = 0; k < 16; ++k) {
      float4 w = w4[k];
      const float* xp = dv + k * 4;
      s += w.x * xp[0] + w.y * xp[1] + w.z * xp[2] + w.w * xp[3];
    }
    dl[t][i] = (s > 15.f) ? s : __logf(1.f + __expf(s));
  }
  __syncthreads();

  // P5: scan. thread -> channel d = tid>>2, state slice sg = tid&3 (16 states).
  // y (incl. D*xs skip) written into sp[t][0..63] (d_in columns, now dead).
  {
    int d = tid >> 2, sg = tid & 3;
    float A_[16], h[16];
    #pragma unroll
    for (int j = 0; j < 16; ++j) {
      A_[j] = -__expf(Alog[d * 64 + sg * 16 + j]);
      h[j] = 0.f;
    }
    float Dd = Dv[d];
    for (int t = 0; t < L; ++t) {
      float dlt = dl[t][d];
      float bb  = dlt * sp[t][64 + d];             // B_bar = delta * Bp
      const float* cp = &sp[t][128 + sg * 16];     // Cp slice
      float part = 0.f;
      #pragma unroll
      for (int j = 0; j < 16; ++j) {
        float ab = __expf(dlt * A_[j]);            // A_bar
        h[j] = ab * h[j] + bb;
        part += h[j] * cp[j];
      }
      part += __shfl_xor(part, 1);
      part += __shfl_xor(part, 2);
      if (sg == 0) sp[t][d] = part + Dd * xs[t][d];
    }
  }
  __syncthreads();

  // P6: out += (y * silu(z)) @ Wout^T  (f32 atomic accumulate over directions)
  for (int e = tid; e < L * 32; e += 256) {
    int t = e >> 5, c = e & 31;
    const float* yv = sp[t];                       // y in cols 0..63
    const float* gv = gz[t];
    const float4* w4 = reinterpret_cast<const float4*>(Wout + c * 64);
    float s = 0.f;
    #pragma unroll
    for (int i = 0; i < 16; ++i) {
      float4 w = w4[i];
      const float* yp = yv + i * 4;
      const float* gp = gv + i * 4;
      s += w.x * yp[0] * gp[0] + w.y * yp[1] * gp[1]
         + w.z * yp[2] * gp[2] + w.w * yp[3] * gp[3];
    }
    atomicAdd(&out[(pbase + t * pstride) * 32 + c], s);
  }
}

extern "C" void kernel_launch(void* const* d_in, const int* in_sizes, int n_in,
                              void* d_out, int out_size, void* d_ws, size_t ws_size,
                              hipStream_t stream) {
  const float* x     = (const float*)d_in[0];
  const float* Win   = (const float*)d_in[1];
  const float* convw = (const float*)d_in[2];
  const float* convb = (const float*)d_in[3];
  const float* Wx    = (const float*)d_in[4];
  const float* Wdt   = (const float*)d_in[5];
  const float* bdt   = (const float*)d_in[6];
  const float* Alog  = (const float*)d_in[7];
  const float* Dv    = (const float*)d_in[8];
  const float* Wout  = (const float*)d_in[9];

  float* out = (float*)d_out;            // f32 output experiment

  hipMemsetAsync(out, 0, (size_t)NPIX * 32 * sizeof(float), stream);
  k_seq<<<NBLK, 256, 0, stream>>>(x, Win, convw, convb, Wx, Wdt, bdt, Alog, Dv,
                                  Wout, out);
}

// Round 7
// 321.265 us; speedup vs baseline: 1.0287x; 1.0287x over previous
//
#include <hip/hip_runtime.h>
#include <hip/hip_bf16.h>

// SpatialMamba — optimized pipeline (round-4 structure + validated f32 output).
//   memset acc=0
//   K0: M = W_dt @ W_x[0:64]      (folds delta's two GEMVs into one, exact)
//   K1: per pixel: xz = x@W_in^T -> xraw (f32), silu(z) (f32)   [shared by 4 dirs]
//   K2: per (dir, seq): conv+silu, {delta,Bp,Cp} GEMVs, 48-step scan,
//       atomicAdd (y + D*xs) into acc   [gate+W_out linear -> sum dirs first]
//   K3: out = (acc * silu_z) @ W_out^T -> f32 d_out
// LDS in K2 = 48 KB -> 3 blocks/CU -> 768 blocks in exactly one round.

constexpr int BN = 4, SL = 48;
constexpr int NPIX = BN * SL * SL;     // 9216
constexpr int L = SL;
constexpr int NSEQ = BN * SL;          // 192
constexpr int NBLK = 4 * NSEQ;         // 768

// ---------------- K0: M[i][d] = sum_s W_dt[i][s] * W_x[s][d] ----------------
__global__ __launch_bounds__(256) void k_precompute_M(
    const float* __restrict__ Wdt, const float* __restrict__ Wx,
    float* __restrict__ M) {
  int e = blockIdx.x * 256 + threadIdx.x;    // 0..4095
  int i = e >> 6, d = e & 63;
  float s = 0.f;
  #pragma unroll 8
  for (int t = 0; t < 64; ++t) s += Wdt[i * 64 + t] * Wx[t * 64 + d];
  M[e] = s;
}

// ---------------- K1: pointwise in-projection (shared across directions) ----
__global__ __launch_bounds__(256) void k_pointwise(
    const float* __restrict__ x, const float* __restrict__ Win,
    float* __restrict__ xraw, float* __restrict__ slz) {
  __shared__ float xf[4 * 32];
  int tid = threadIdx.x;
  int pix0 = blockIdx.x * 4;
  if (tid < 128) xf[tid] = x[pix0 * 32 + tid];
  __syncthreads();
  int p = tid >> 6, d = tid & 63;
  const float* xv = xf + p * 32;
  const float4* w0 = reinterpret_cast<const float4*>(Win + d * 32);
  const float4* w1 = reinterpret_cast<const float4*>(Win + (64 + d) * 32);
  float s0 = 0.f, s1 = 0.f;
  #pragma unroll
  for (int i = 0; i < 8; ++i) {
    float4 a = w0[i];
    float4 b = w1[i];
    const float* xr = xv + i * 4;
    s0 += a.x * xr[0] + a.y * xr[1] + a.z * xr[2] + a.w * xr[3];
    s1 += b.x * xr[0] + b.y * xr[1] + b.z * xr[2] + b.w * xr[3];
  }
  int pix = pix0 + p;
  xraw[pix * 64 + d] = s0;
  slz[pix * 64 + d]  = s1 / (1.f + __expf(-s1));   // silu(z)
}

// ---------------- K2: per-(dir,seq) conv + projections + scan ----------------
__global__ __launch_bounds__(256) void k_scan(
    const float* __restrict__ xraw, const float* __restrict__ Ms,
    const float* __restrict__ Wx, const float* __restrict__ convw,
    const float* __restrict__ convb, const float* __restrict__ bdt,
    const float* __restrict__ Alog, const float* __restrict__ Dv,
    float* __restrict__ acc) {
  __shared__ float xs_s[L * 64];     // post-conv silu'd x_ssm   (12 KB)
  __shared__ float u_s[L * 192];     // A/B: xr[48][64]; C/D: {delta,Bp,Cp}[48][192] (36 KB)

  int tid = threadIdx.x;
  int bid = blockIdx.x;
  int dir = bid / NSEQ;
  int seq = bid % NSEQ;
  int b = seq / SL, q = seq % SL;
  int pbase, pstride;
  if (dir == 0)      { pbase = (b * SL) * SL + q;           pstride = SL;  }  // H fwd
  else if (dir == 1) { pbase = (b * SL + SL - 1) * SL + q;  pstride = -SL; }  // H bwd
  else if (dir == 2) { pbase = (b * SL + q) * SL;           pstride = 1;   }  // W fwd
  else               { pbase = (b * SL + q) * SL + SL - 1;  pstride = -1;  }  // W bwd

  int wv = tid >> 6, lane = tid & 63;

  // Phase A: stage xraw rows (coalesced 256B per row)
  float* xr = u_s;
  for (int t = wv; t < L; t += 4)
    xr[t * 64 + lane] = xraw[(pbase + t * pstride) * 64 + lane];
  __syncthreads();

  // Phase B: causal depthwise conv k=4 (left zero-pad) + silu
  for (int e = tid; e < L * 64; e += 256) {
    int t = e >> 6, d = e & 63;
    float4 cw = reinterpret_cast<const float4*>(convw)[d];
    float s = convb[d] + xr[t * 64 + d] * cw.w;
    if (t >= 1) s += xr[(t - 1) * 64 + d] * cw.z;
    if (t >= 2) s += xr[(t - 2) * 64 + d] * cw.y;
    if (t >= 3) s += xr[(t - 3) * 64 + d] * cw.x;
    xs_s[e] = s / (1.f + __expf(-s));
  }
  __syncthreads();

  // Phase C: 144 jobs = 48 t x {delta (M-fold), Bp, Cp}
  for (int job = wv; job < 144; job += 4) {
    int t = job / 3, ch = job % 3;
    const float* xv = xs_s + t * 64;
    float s = 0.f;
    if (ch == 0) {
      const float4* m4 = reinterpret_cast<const float4*>(Ms + lane * 64);
      #pragma unroll
      for (int i = 0; i < 16; ++i) {
        float4 w = m4[i];
        const float* xp = xv + i * 4;
        s += w.x * xp[0] + w.y * xp[1] + w.z * xp[2] + w.w * xp[3];
      }
      s += bdt[lane];
      s = (s > 15.f) ? s : __logf(1.f + __expf(s));    // softplus -> delta
      u_s[t * 192 + lane] = s;
    } else {
      const float4* w4 = reinterpret_cast<const float4*>(Wx + (ch * 64 + lane) * 64);
      #pragma unroll
      for (int i = 0; i < 16; ++i) {
        float4 w = w4[i];
        const float* xp = xv + i * 4;
        s += w.x * xp[0] + w.y * xp[1] + w.z * xp[2] + w.w * xp[3];
      }
      u_s[t * 192 + ch * 64 + lane] = s;               // Bp (ch=1) / Cp (ch=2)
    }
  }
  __syncthreads();

  // Phase D: 48-step scan. thread -> d = tid>>2, state slice sg = tid&3
  int d = tid >> 2, sg = tid & 3;
  float A_[16], h[16];
  #pragma unroll
  for (int j = 0; j < 16; ++j) {
    A_[j] = -__expf(Alog[d * 64 + sg * 16 + j]);
    h[j] = 0.f;
  }
  float Dd = Dv[d];
  for (int t = 0; t < L; ++t) {
    float dlt = u_s[t * 192 + d];
    float bb  = dlt * u_s[t * 192 + 64 + d];           // B_bar = delta * Bp
    const float* cp = u_s + t * 192 + 128 + sg * 16;
    float part = 0.f;
    #pragma unroll
    for (int j = 0; j < 16; ++j) {
      float ab = __expf(dlt * A_[j]);                  // A_bar
      h[j] = ab * h[j] + bb;
      part += h[j] * cp[j];
    }
    part += __shfl_xor(part, 1);
    part += __shfl_xor(part, 2);
    if (sg == 0) {
      float yv = part + Dd * xs_s[t * 64 + d];         // + skip D*x_ssm
      atomicAdd(&acc[(pbase + t * pstride) * 64 + d], yv);
    }
  }
}

// ---------------- K3: gate + out-projection -> f32 d_out ----------------
__global__ __launch_bounds__(256) void k_out(
    const float* __restrict__ acc, const float* __restrict__ slz,
    const float* __restrict__ Wout, float* __restrict__ out) {
  int gid = blockIdx.x * 256 + threadIdx.x;
  int pix = gid >> 5, c = gid & 31;
  const float4* w4 = reinterpret_cast<const float4*>(Wout + c * 64);
  const float* ap = acc + pix * 64;
  const float* gp = slz + pix * 64;
  float s = 0.f;
  #pragma unroll
  for (int i = 0; i < 16; ++i) {
    float4 w = w4[i];
    const float* a4 = ap + i * 4;
    const float* g4 = gp + i * 4;
    s += w.x * a4[0] * g4[0] + w.y * a4[1] * g4[1]
       + w.z * a4[2] * g4[2] + w.w * a4[3] * g4[3];
  }
  out[gid] = s;
}

extern "C" void kernel_launch(void* const* d_in, const int* in_sizes, int n_in,
                              void* d_out, int out_size, void* d_ws, size_t ws_size,
                              hipStream_t stream) {
  const float* x     = (const float*)d_in[0];
  const float* Win   = (const float*)d_in[1];
  const float* convw = (const float*)d_in[2];
  const float* convb = (const float*)d_in[3];
  const float* Wx    = (const float*)d_in[4];
  const float* Wdt   = (const float*)d_in[5];
  const float* bdt   = (const float*)d_in[6];
  const float* Alog  = (const float*)d_in[7];
  const float* Dv    = (const float*)d_in[8];
  const float* Wout  = (const float*)d_in[9];

  float* xraw = (float*)d_ws;              // [9216][64] f32
  float* slz  = xraw + NPIX * 64;          // [9216][64] f32
  float* accb = slz + NPIX * 64;           // [9216][64] f32
  float* Ms   = accb + NPIX * 64;          // [64][64]  f32

  hipMemsetAsync(accb, 0, (size_t)NPIX * 64 * sizeof(float), stream);
  k_precompute_M<<<16, 256, 0, stream>>>(Wdt, Wx, Ms);
  k_pointwise<<<NPIX / 4, 256, 0, stream>>>(x, Win, xraw, slz);
  k_scan<<<NBLK, 256, 0, stream>>>(xraw, Ms, Wx, convw, convb, bdt, Alog, Dv, accb);
  k_out<<<NPIX * 32 / 256, 256, 0, stream>>>(accb, slz, Wout, (float*)d_out);
}

// Round 8
// 142.461 us; speedup vs baseline: 2.3198x; 2.2551x over previous
//
#include <hip/hip_runtime.h>
#include <hip/hip_bf16.h>

// SpatialMamba — round 8: kill the transposed weight access.
// All per-lane-row GEMV reads (64 cache lines/instr) replaced by k-major
// transposed weights (coalesced 256B/instr) + LDS-broadcast activations.
//   memset acc=0
//   Kp: prep: M^T = (W_dt@W_x[0:64])^T, plus WxT1/WxT2/WinT/WoutT transposes
//   K1: per pixel: xraw = x@W_in^T[0:64], slz = silu(x@W_in^T[64:128])
//   K2: per (dir,seq): conv+silu -> rank-1 GEMVs {delta,Bp,Cp} -> 48-step scan
//       -> atomicAdd (y + D*xs) into acc  [gate+W_out linear -> sum dirs first]
//   K3: out = (acc * slz) @ W_out^T  (f32)

constexpr int BN = 4, SL = 48;
constexpr int NPIX = BN * SL * SL;     // 9216
constexpr int L = SL;
constexpr int NSEQ = BN * SL;          // 192
constexpr int NBLK = 4 * NSEQ;         // 768

// ---------------- Kp: fold M and build transposed weights ----------------
__global__ __launch_bounds__(256) void k_prep(
    const float* __restrict__ Wdt, const float* __restrict__ Wx,
    const float* __restrict__ Win, const float* __restrict__ Wout,
    float* __restrict__ MsT, float* __restrict__ WxT1, float* __restrict__ WxT2,
    float* __restrict__ WinT, float* __restrict__ WoutT) {
  int e = blockIdx.x * 256 + threadIdx.x;
  if (e < 4096) {                      // MsT[k][i] = sum_s Wdt[i][s]*Wx[s][k]
    int i = e >> 6, d = e & 63;
    float s = 0.f;
    #pragma unroll 8
    for (int t = 0; t < 64; ++t) s += Wdt[i * 64 + t] * Wx[t * 64 + d];
    MsT[d * 64 + i] = s;
  } else if (e < 8192) {               // WxT1[k][r] = Wx[64+r][k]   (Bp rows)
    int e2 = e - 4096; int k = e2 >> 6, r = e2 & 63;
    WxT1[k * 64 + r] = Wx[(64 + r) * 64 + k];
  } else if (e < 12288) {              // WxT2[k][r] = Wx[128+r][k]  (Cp rows)
    int e2 = e - 8192; int k = e2 >> 6, r = e2 & 63;
    WxT2[k * 64 + r] = Wx[(128 + r) * 64 + k];
  } else if (e < 16384) {              // WinT[k][j] = Win[j][k]
    int e2 = e - 12288; int j = e2 & 127, k = e2 >> 7;
    WinT[k * 128 + j] = Win[j * 32 + k];
  } else if (e < 18432) {              // WoutT[d][c] = Wout[c][d]
    int e2 = e - 16384; int c = e2 & 31, d = e2 >> 5;
    WoutT[d * 32 + c] = Wout[c * 64 + d];
  }
}

// ---------------- K1: pointwise in-projection (coalesced WinT) ----------------
__global__ __launch_bounds__(256) void k_pointwise(
    const float* __restrict__ x, const float* __restrict__ WinT,
    float* __restrict__ xraw, float* __restrict__ slz) {
  __shared__ float xf[4 * 32];
  int tid = threadIdx.x;
  int pix0 = blockIdx.x * 4;
  if (tid < 128) xf[tid] = x[pix0 * 32 + tid];
  __syncthreads();
  int p = tid >> 6, lane = tid & 63;
  const float* xv = xf + p * 32;
  float s0 = 0.f, s1 = 0.f;
  #pragma unroll
  for (int k = 0; k < 32; ++k) {
    float xk = xv[k];
    s0 += WinT[k * 128 + lane] * xk;         // coalesced 256B
    s1 += WinT[k * 128 + 64 + lane] * xk;    // coalesced 256B
  }
  int pix = pix0 + p;
  xraw[pix * 64 + lane] = s0;
  slz[pix * 64 + lane]  = s1 / (1.f + __expf(-s1));
}

// ---------------- K2: per-(dir,seq) conv + rank-1 GEMVs + scan ----------------
__global__ __launch_bounds__(256) void k_scan(
    const float* __restrict__ xraw, const float* __restrict__ MsT,
    const float* __restrict__ WxT1, const float* __restrict__ WxT2,
    const float* __restrict__ convw, const float* __restrict__ convb,
    const float* __restrict__ bdt, const float* __restrict__ Alog,
    const float* __restrict__ Dv, float* __restrict__ acc) {
  __shared__ float xs_s[L * 64];     // conv+silu x_ssm (12 KB)
  __shared__ float u_s[L * 192];     // A/B: xr; C/D: {delta,Bp,Cp} (36 KB)

  int tid = threadIdx.x;
  int bid = blockIdx.x;
  int dir = bid / NSEQ;
  int seq = bid % NSEQ;
  int b = seq / SL, q = seq % SL;
  int pbase, pstride;
  if (dir == 0)      { pbase = (b * SL) * SL + q;           pstride = SL;  }
  else if (dir == 1) { pbase = (b * SL + SL - 1) * SL + q;  pstride = -SL; }
  else if (dir == 2) { pbase = (b * SL + q) * SL;           pstride = 1;   }
  else               { pbase = (b * SL + q) * SL + SL - 1;  pstride = -1;  }

  int wv = tid >> 6, lane = tid & 63;

  // Phase A: stage xraw rows (coalesced 256B per row)
  float* xr = u_s;
  for (int t = wv; t < L; t += 4)
    xr[t * 64 + lane] = xraw[(pbase + t * pstride) * 64 + lane];
  __syncthreads();

  // Phase B: causal depthwise conv k=4 + silu
  for (int e = tid; e < L * 64; e += 256) {
    int t = e >> 6, d = e & 63;
    float4 cw = reinterpret_cast<const float4*>(convw)[d];
    float s = convb[d] + xr[t * 64 + d] * cw.w;
    if (t >= 1) s += xr[(t - 1) * 64 + d] * cw.z;
    if (t >= 2) s += xr[(t - 2) * 64 + d] * cw.y;
    if (t >= 3) s += xr[(t - 3) * 64 + d] * cw.x;
    xs_s[e] = s / (1.f + __expf(-s));
  }
  __syncthreads();

  // Phase C: rank-1 update GEMVs. Wave wv owns t in [wv*12, wv*12+12).
  // lane = output channel; weights coalesced k-major; xs via b128 broadcast.
  {
    int tr = wv * 12;
    float aD[12], aB[12], aC[12];
    #pragma unroll
    for (int j = 0; j < 12; ++j) { aD[j] = 0.f; aB[j] = 0.f; aC[j] = 0.f; }
    for (int k4 = 0; k4 < 16; ++k4) {
      int k0 = k4 * 4;
      float wd0 = MsT[(k0 + 0) * 64 + lane], wd1 = MsT[(k0 + 1) * 64 + lane];
      float wd2 = MsT[(k0 + 2) * 64 + lane], wd3 = MsT[(k0 + 3) * 64 + lane];
      float wb0 = WxT1[(k0 + 0) * 64 + lane], wb1 = WxT1[(k0 + 1) * 64 + lane];
      float wb2 = WxT1[(k0 + 2) * 64 + lane], wb3 = WxT1[(k0 + 3) * 64 + lane];
      float wc0 = WxT2[(k0 + 0) * 64 + lane], wc1 = WxT2[(k0 + 1) * 64 + lane];
      float wc2 = WxT2[(k0 + 2) * 64 + lane], wc3 = WxT2[(k0 + 3) * 64 + lane];
      #pragma unroll
      for (int j = 0; j < 12; ++j) {
        float4 x4 = *reinterpret_cast<const float4*>(xs_s + (tr + j) * 64 + k0);
        aD[j] += wd0 * x4.x + wd1 * x4.y + wd2 * x4.z + wd3 * x4.w;
        aB[j] += wb0 * x4.x + wb1 * x4.y + wb2 * x4.z + wb3 * x4.w;
        aC[j] += wc0 * x4.x + wc1 * x4.y + wc2 * x4.z + wc3 * x4.w;
      }
    }
    float bdl = bdt[lane];
    #pragma unroll
    for (int j = 0; j < 12; ++j) {
      float s = aD[j] + bdl;
      s = (s > 15.f) ? s : __logf(1.f + __expf(s));    // softplus -> delta
      u_s[(tr + j) * 192 + lane]       = s;
      u_s[(tr + j) * 192 + 64 + lane]  = aB[j];        // Bp
      u_s[(tr + j) * 192 + 128 + lane] = aC[j];        // Cp
    }
  }
  __syncthreads();

  // Phase D: 48-step scan. thread -> d = tid>>2, state slice sg = tid&3
  int d = tid >> 2, sg = tid & 3;
  float A_[16], h[16];
  #pragma unroll
  for (int j = 0; j < 16; ++j) {
    A_[j] = -__expf(Alog[d * 64 + sg * 16 + j]);
    h[j] = 0.f;
  }
  float Dd = Dv[d];
  for (int t = 0; t < L; ++t) {
    float dlt = u_s[t * 192 + d];
    float bb  = dlt * u_s[t * 192 + 64 + d];
    const float* cp = u_s + t * 192 + 128 + sg * 16;
    float part = 0.f;
    #pragma unroll
    for (int j = 0; j < 16; ++j) {
      float ab = __expf(dlt * A_[j]);
      h[j] = ab * h[j] + bb;
      part += h[j] * cp[j];
    }
    part += __shfl_xor(part, 1);
    part += __shfl_xor(part, 2);
    if (sg == 0) {
      float yv = part + Dd * xs_s[t * 64 + d];
      atomicAdd(&acc[(pbase + t * pstride) * 64 + d], yv);
    }
  }
}

// ---------------- K3: gate + out-projection (coalesced WoutT) ----------------
__global__ __launch_bounds__(256) void k_out(
    const float* __restrict__ acc, const float* __restrict__ slz,
    const float* __restrict__ WoutT, float* __restrict__ out) {
  __shared__ float ag[8 * 64];
  int tid = threadIdx.x;
  int pix0 = blockIdx.x * 8;
  #pragma unroll
  for (int e = tid; e < 512; e += 256)
    ag[e] = acc[pix0 * 64 + e] * slz[pix0 * 64 + e];
  __syncthreads();
  int pl = tid >> 5, c = tid & 31;
  const float* av = ag + pl * 64;
  float s = 0.f;
  #pragma unroll
  for (int d = 0; d < 64; ++d)
    s += WoutT[d * 32 + c] * av[d];          // wave reads one 128B line
  out[(pix0 + pl) * 32 + c] = s;
}

extern "C" void kernel_launch(void* const* d_in, const int* in_sizes, int n_in,
                              void* d_out, int out_size, void* d_ws, size_t ws_size,
                              hipStream_t stream) {
  const float* x     = (const float*)d_in[0];
  const float* Win   = (const float*)d_in[1];
  const float* convw = (const float*)d_in[2];
  const float* convb = (const float*)d_in[3];
  const float* Wx    = (const float*)d_in[4];
  const float* Wdt   = (const float*)d_in[5];
  const float* bdt   = (const float*)d_in[6];
  const float* Alog  = (const float*)d_in[7];
  const float* Dv    = (const float*)d_in[8];
  const float* Wout  = (const float*)d_in[9];

  float* xraw  = (float*)d_ws;                // [9216][64]
  float* slz   = xraw + NPIX * 64;            // [9216][64]
  float* accb  = slz + NPIX * 64;             // [9216][64]
  float* MsT   = accb + NPIX * 64;            // [64][64]
  float* WxT1  = MsT + 4096;                  // [64][64]
  float* WxT2  = WxT1 + 4096;                 // [64][64]
  float* WinT  = WxT2 + 4096;                 // [32][128]
  float* WoutT = WinT + 4096;                 // [64][32]

  hipMemsetAsync(accb, 0, (size_t)NPIX * 64 * sizeof(float), stream);
  k_prep<<<72, 256, 0, stream>>>(Wdt, Wx, Win, Wout, MsT, WxT1, WxT2, WinT, WoutT);
  k_pointwise<<<NPIX / 4, 256, 0, stream>>>(x, WinT, xraw, slz);
  k_scan<<<NBLK, 256, 0, stream>>>(xraw, MsT, WxT1, WxT2, convw, convb, bdt,
                                   Alog, Dv, accb);
  k_out<<<NPIX / 8, 256, 0, stream>>>(accb, slz, WoutT, (float*)d_out);
}

// Round 9
// 135.854 us; speedup vs baseline: 2.4327x; 1.0486x over previous
//
#include <hip/hip_runtime.h>
#include <hip/hip_bf16.h>

// SpatialMamba — round 9: dispatch-count reduction + full fusion.
//   K_pre (632 blocks): [0..575] in-projection, 16 pix/block, Win transposed
//                       in-LDS; [576..631] weight packing (PMs/PB/PC/PO);
//                       all blocks also grid-stride-zero d_out.
//   K_scan (768 blocks): per (dir,seq) conv+silu -> packed-f4 GEMVs
//                       {delta,Bp,Cp} -> 48-step scan -> gate(slz) ->
//                       out-projection -> atomicAdd into d_out (f32).
// 2 dispatches total. k_scan LDS = 48KB -> 3 blocks/CU, 768 = one full round.

constexpr int BN = 4, SL = 48;
constexpr int NPIX = BN * SL * SL;     // 9216
constexpr int L = SL;
constexpr int NSEQ = BN * SL;          // 192
constexpr int NBLK = 4 * NSEQ;         // 768
constexpr int PIXPB = 16;              // pixels per k_pre block
constexpr int NPWB = NPIX / PIXPB;     // 576
constexpr int NPREP = 56;              // 14336 packed-weight elements
constexpr int NPREB = NPWB + NPREP;    // 632

// ---------------- K_pre: zero out + in-proj + weight packing ----------------
__global__ __launch_bounds__(256) void k_pre(
    const float* __restrict__ x, const float* __restrict__ Win,
    const float* __restrict__ Wdt, const float* __restrict__ Wx,
    const float* __restrict__ Wout,
    float* __restrict__ xraw, float* __restrict__ slz,
    float* __restrict__ PMs, float* __restrict__ PB,
    float* __restrict__ PC, float* __restrict__ PO,
    float* __restrict__ out) {
  __shared__ float xf[PIXPB * 32];   // 2 KB
  __shared__ float wt[32 * 129];     // 16.5 KB transposed Win, pad->conflict-free
  int bid = blockIdx.x, tid = threadIdx.x;

  // zero d_out (grid-stride across all 632 blocks; k_scan runs after)
  for (int e = bid * 256 + tid; e < NPIX * 32; e += NPREB * 256) out[e] = 0.f;

  if (bid < NPWB) {
    int pix0 = bid * PIXPB;
    for (int e = tid; e < PIXPB * 32; e += 256) xf[e] = x[pix0 * 32 + e];
    for (int e = tid; e < 4096; e += 256) {
      int j = e >> 5, k = e & 31;
      wt[k * 129 + j] = Win[e];                    // Win[j][k] -> wt[k][j]
    }
    __syncthreads();
    int g = tid >> 6, lane = tid & 63;
    float s0[4] = {0.f, 0.f, 0.f, 0.f}, s1[4] = {0.f, 0.f, 0.f, 0.f};
    for (int k = 0; k < 32; ++k) {
      float w0 = wt[k * 129 + lane];               // Win[lane][k]
      float w1 = wt[k * 129 + 64 + lane];          // Win[64+lane][k]
      #pragma unroll
      for (int pp = 0; pp < 4; ++pp) {
        float xk = xf[(g * 4 + pp) * 32 + k];      // wave-uniform broadcast
        s0[pp] += w0 * xk;
        s1[pp] += w1 * xk;
      }
    }
    #pragma unroll
    for (int pp = 0; pp < 4; ++pp) {
      int pix = pix0 + g * 4 + pp;
      xraw[pix * 64 + lane] = s0[pp];
      float z = s1[pp];
      slz[pix * 64 + lane] = z / (1.f + __expf(-z));
    }
  } else {
    // weight packing: P[k4][r][kk] = W^T[k4*4+kk][r]  (float4-loadable)
    int e = (bid - NPWB) * 256 + tid;              // 0..14335
    if (e < 4096) {                                // PMs from M = Wdt@Wx[0:64]
      int i = e >> 6, d = e & 63;                  // i=out ch, d=contraction k
      float s = 0.f;
      #pragma unroll 8
      for (int t = 0; t < 64; ++t) s += Wdt[i * 64 + t] * Wx[t * 64 + d];
      PMs[((d >> 2) * 64 + i) * 4 + (d & 3)] = s;
    } else if (e < 8192) {                         // PB: Wx[64+r][k] (Bp)
      int e2 = e - 4096; int k = e2 >> 6, r = e2 & 63;
      PB[((k >> 2) * 64 + r) * 4 + (k & 3)] = Wx[(64 + r) * 64 + k];
    } else if (e < 12288) {                        // PC: Wx[128+r][k] (Cp)
      int e2 = e - 8192; int k = e2 >> 6, r = e2 & 63;
      PC[((k >> 2) * 64 + r) * 4 + (k & 3)] = Wx[(128 + r) * 64 + k];
    } else {                                       // PO: Wout[c][d]
      int e2 = e - 12288; int c = e2 & 31, d = e2 >> 5;
      PO[((d >> 2) * 32 + c) * 4 + (d & 3)] = Wout[c * 64 + d];
    }
  }
}

// ---------------- K_scan: conv + GEMVs + scan + gate + out-proj ----------------
__global__ __launch_bounds__(256) void k_scan(
    const float* __restrict__ xraw, const float* __restrict__ slz,
    const float* __restrict__ PMs, const float* __restrict__ PB,
    const float* __restrict__ PC, const float* __restrict__ PO,
    const float* __restrict__ convw, const float* __restrict__ convb,
    const float* __restrict__ bdt, const float* __restrict__ Alog,
    const float* __restrict__ Dv, float* __restrict__ out) {
  __shared__ float xs_s[L * 64];     // conv+silu x_ssm (12 KB)
  __shared__ float u_s[L * 192];     // A: xr; C/D: {delta,Bp,Cp}; y/yg in cols 0..63

  int tid = threadIdx.x;
  int bid = blockIdx.x;
  int dir = bid / NSEQ;
  int seq = bid % NSEQ;
  int b = seq / SL, q = seq % SL;
  int pbase, pstride;
  if (dir == 0)      { pbase = (b * SL) * SL + q;           pstride = SL;  }
  else if (dir == 1) { pbase = (b * SL + SL - 1) * SL + q;  pstride = -SL; }
  else if (dir == 2) { pbase = (b * SL + q) * SL;           pstride = 1;   }
  else               { pbase = (b * SL + q) * SL + SL - 1;  pstride = -1;  }

  int wv = tid >> 6, lane = tid & 63;

  // Phase A: stage xraw rows (coalesced 256B per row)
  float* xr = u_s;
  for (int t = wv; t < L; t += 4)
    xr[t * 64 + lane] = xraw[(pbase + t * pstride) * 64 + lane];
  __syncthreads();

  // Phase B: causal depthwise conv k=4 + silu
  for (int e = tid; e < L * 64; e += 256) {
    int t = e >> 6, d = e & 63;
    float4 cw = reinterpret_cast<const float4*>(convw)[d];
    float s = convb[d] + xr[t * 64 + d] * cw.w;
    if (t >= 1) s += xr[(t - 1) * 64 + d] * cw.z;
    if (t >= 2) s += xr[(t - 2) * 64 + d] * cw.y;
    if (t >= 3) s += xr[(t - 3) * 64 + d] * cw.x;
    xs_s[e] = s / (1.f + __expf(-s));
  }
  __syncthreads();

  // Phase C: rank-1 GEMVs, packed-float4 weights. Wave wv owns 12 t's.
  {
    int tr = wv * 12;
    float aD[12], aB[12], aC[12];
    #pragma unroll
    for (int j = 0; j < 12; ++j) { aD[j] = 0.f; aB[j] = 0.f; aC[j] = 0.f; }
    const float4* pms = reinterpret_cast<const float4*>(PMs);
    const float4* pb  = reinterpret_cast<const float4*>(PB);
    const float4* pc  = reinterpret_cast<const float4*>(PC);
    for (int k4 = 0; k4 < 16; ++k4) {
      float4 wd = pms[k4 * 64 + lane];
      float4 wb = pb[k4 * 64 + lane];
      float4 wc = pc[k4 * 64 + lane];
      #pragma unroll
      for (int j = 0; j < 12; ++j) {
        float4 x4 = *reinterpret_cast<const float4*>(xs_s + (tr + j) * 64 + k4 * 4);
        aD[j] += wd.x * x4.x + wd.y * x4.y + wd.z * x4.z + wd.w * x4.w;
        aB[j] += wb.x * x4.x + wb.y * x4.y + wb.z * x4.z + wb.w * x4.w;
        aC[j] += wc.x * x4.x + wc.y * x4.y + wc.z * x4.z + wc.w * x4.w;
      }
    }
    float bdl = bdt[lane];
    #pragma unroll
    for (int j = 0; j < 12; ++j) {
      float s = aD[j] + bdl;
      s = (s > 15.f) ? s : __logf(1.f + __expf(s));    // softplus -> delta
      u_s[(tr + j) * 192 + lane]       = s;
      u_s[(tr + j) * 192 + 64 + lane]  = aB[j];        // Bp
      u_s[(tr + j) * 192 + 128 + lane] = aC[j];        // Cp
    }
  }
  __syncthreads();

  // Phase D: 48-step scan. d = tid>>2, sg = tid&3. y overwrites delta col.
  {
    int d = tid >> 2, sg = tid & 3;
    float A_[16], h[16];
    #pragma unroll
    for (int j = 0; j < 16; ++j) {
      A_[j] = -__expf(Alog[d * 64 + sg * 16 + j]);
      h[j] = 0.f;
    }
    float Dd = Dv[d];
    for (int t = 0; t < L; ++t) {
      float dlt = u_s[t * 192 + d];
      float bb  = dlt * u_s[t * 192 + 64 + d];
      const float* cp = u_s + t * 192 + 128 + sg * 16;
      float part = 0.f;
      #pragma unroll
      for (int j = 0; j < 16; ++j) {
        float ab = __expf(dlt * A_[j]);
        h[j] = ab * h[j] + bb;
        part += h[j] * cp[j];
      }
      part += __shfl_xor(part, 1);
      part += __shfl_xor(part, 2);
      // delta[t][d] consumed this step by exactly these 4 lanes (same wave,
      // lockstep) -> safe in-place y write
      if (sg == 0) u_s[t * 192 + d] = part + Dd * xs_s[t * 64 + d];
    }
  }
  __syncthreads();

  // P6a: gate y with silu(z) (coalesced global read, L2-hot)
  for (int e = tid; e < L * 64; e += 256) {
    int t = e >> 6, d = e & 63;
    u_s[t * 192 + d] *= slz[(pbase + t * pstride) * 64 + d];
  }
  __syncthreads();

  // P6b: out-projection (packed-float4 weights) + atomic accumulate
  for (int e = tid; e < L * 32; e += 256) {
    int t = e >> 5, c = e & 31;
    const float4* po = reinterpret_cast<const float4*>(PO);
    const float* yv = u_s + t * 192;
    float s = 0.f;
    #pragma unroll
    for (int d4 = 0; d4 < 16; ++d4) {
      float4 w = po[d4 * 32 + c];
      const float* yp = yv + d4 * 4;
      s += w.x * yp[0] + w.y * yp[1] + w.z * yp[2] + w.w * yp[3];
    }
    atomicAdd(&out[(pbase + t * pstride) * 32 + c], s);
  }
}

extern "C" void kernel_launch(void* const* d_in, const int* in_sizes, int n_in,
                              void* d_out, int out_size, void* d_ws, size_t ws_size,
                              hipStream_t stream) {
  const float* x     = (const float*)d_in[0];
  const float* Win   = (const float*)d_in[1];
  const float* convw = (const float*)d_in[2];
  const float* convb = (const float*)d_in[3];
  const float* Wx    = (const float*)d_in[4];
  const float* Wdt   = (const float*)d_in[5];
  const float* bdt   = (const float*)d_in[6];
  const float* Alog  = (const float*)d_in[7];
  const float* Dv    = (const float*)d_in[8];
  const float* Wout  = (const float*)d_in[9];

  float* xraw = (float*)d_ws;                // [9216][64]
  float* slz  = xraw + NPIX * 64;            // [9216][64]
  float* PMs  = slz + NPIX * 64;             // [16][64][4]
  float* PB   = PMs + 4096;                  // [16][64][4]
  float* PC   = PB + 4096;                   // [16][64][4]
  float* PO   = PC + 4096;                   // [16][32][4]
  float* out  = (float*)d_out;

  k_pre<<<NPREB, 256, 0, stream>>>(x, Win, Wdt, Wx, Wout, xraw, slz,
                                   PMs, PB, PC, PO, out);
  k_scan<<<NBLK, 256, 0, stream>>>(xraw, slz, PMs, PB, PC, PO, convw, convb,
                                   bdt, Alog, Dv, out);
}

// Round 11
// 124.202 us; speedup vs baseline: 2.6609x; 1.0938x over previous
//
#include <hip/hip_runtime.h>
#include <hip/hip_bf16.h>
#include <stdint.h>

// SpatialMamba — round 11: round-10 design with __exp2f -> exp2f fix.
// Phase-D exp collapse (A arithmetic in s => 2 exps instead of 16) +
// phase-C Bp/Cp via bf16 MFMA. Two dispatches (k_pre, k_scan).

constexpr int BN = 4, SL = 48;
constexpr int NPIX = BN * SL * SL;     // 9216
constexpr int L = SL;
constexpr int NSEQ = BN * SL;          // 192
constexpr int NBLK = 4 * NSEQ;         // 768
constexpr int PIXPB = 16;
constexpr int NPWB = NPIX / PIXPB;     // 576
constexpr int NPREP = 56;              // 14336 packed elements
constexpr int NPREB = NPWB + NPREP;    // 632

typedef __attribute__((ext_vector_type(8))) short short8;   // 8 bf16 frag
typedef __attribute__((ext_vector_type(4))) float f32x4;    // MFMA accum

#define DEVINL __device__ __forceinline__
DEVINL ushort f2b(float f) {           // f32 -> bf16 bits (RNE)
  uint u = __float_as_uint(f);
  return (ushort)((u + 0x7FFFu + ((u >> 16) & 1u)) >> 16);
}
DEVINL float b2f(ushort u) { return __uint_as_float(((uint)u) << 16); }

// ---------------- K_pre: zero d_out + in-proj + weight packing ----------------
__global__ __launch_bounds__(256) void k_pre(
    const float* __restrict__ x, const float* __restrict__ Win,
    const float* __restrict__ Wdt, const float* __restrict__ Wx,
    const float* __restrict__ Wout,
    float* __restrict__ xraw, float* __restrict__ slz,
    float* __restrict__ PMs, float* __restrict__ PO,
    ushort* __restrict__ PW2, float* __restrict__ out) {
  __shared__ float xf[PIXPB * 32];
  __shared__ float wt[32 * 129];
  int bid = blockIdx.x, tid = threadIdx.x;

  for (int e = bid * 256 + tid; e < NPIX * 32; e += NPREB * 256) out[e] = 0.f;

  if (bid < NPWB) {
    int pix0 = bid * PIXPB;
    for (int e = tid; e < PIXPB * 32; e += 256) xf[e] = x[pix0 * 32 + e];
    for (int e = tid; e < 4096; e += 256) {
      int j = e >> 5, k = e & 31;
      wt[k * 129 + j] = Win[e];
    }
    __syncthreads();
    int g = tid >> 6, lane = tid & 63;
    float s0[4] = {0.f, 0.f, 0.f, 0.f}, s1[4] = {0.f, 0.f, 0.f, 0.f};
    for (int k = 0; k < 32; ++k) {
      float w0 = wt[k * 129 + lane];
      float w1 = wt[k * 129 + 64 + lane];
      #pragma unroll
      for (int pp = 0; pp < 4; ++pp) {
        float xk = xf[(g * 4 + pp) * 32 + k];
        s0[pp] += w0 * xk;
        s1[pp] += w1 * xk;
      }
    }
    #pragma unroll
    for (int pp = 0; pp < 4; ++pp) {
      int pix = pix0 + g * 4 + pp;
      xraw[pix * 64 + lane] = s0[pp];
      float z = s1[pp];
      slz[pix * 64 + lane] = z / (1.f + __expf(-z));
    }
  } else {
    int e = (bid - NPWB) * 256 + tid;            // 0..14335
    if (e < 4096) {                              // PMs: delta-fold, f4-packed
      int i = e >> 6, d = e & 63;
      float s = 0.f;
      #pragma unroll 8
      for (int t = 0; t < 64; ++t) s += Wdt[i * 64 + t] * Wx[t * 64 + d];
      PMs[((d >> 2) * 64 + i) * 4 + (d & 3)] = s;
    } else if (e < 12288) {                      // PW2: bf16 B-frags for Bp/Cp
      int e2 = e - 4096;                         // [nt(8)][ks(2)][l(64)][j(8)]
      int j = e2 & 7, l = (e2 >> 3) & 63, ks = (e2 >> 9) & 1, nt = e2 >> 10;
      int k = ks * 32 + ((l >> 4) * 8) + j;      // contraction index
      int row = 64 + nt * 16 + (l & 15);         // Wx row (Bp/Cp block)
      PW2[e2] = f2b(Wx[row * 64 + k]);
    } else {                                     // PO: out-proj f4-packed
      int e2 = e - 12288; int c = e2 & 31, d = e2 >> 5;
      PO[((d >> 2) * 32 + c) * 4 + (d & 3)] = Wout[c * 64 + d];
    }
  }
}

// ---------------- K_scan ----------------
__global__ __launch_bounds__(256, 4) void k_scan(
    const float* __restrict__ xraw, const float* __restrict__ slz,
    const float* __restrict__ PMs, const ushort* __restrict__ PW2,
    const float* __restrict__ PO,
    const float* __restrict__ convw, const float* __restrict__ convb,
    const float* __restrict__ bdt, const float* __restrict__ Alog,
    const float* __restrict__ Dv, float* __restrict__ out) {
  __shared__ float R1[L * 64];                   // xr staging -> delta -> y (12 KB)
  __shared__ __align__(16) ushort R2u[L * 136];  // Bp|Cp bf16, padded (13.1 KB)
  __shared__ float R3[L * 64];                   // xs f32 (12 KB)
  __shared__ __align__(16) ushort R4u[L * 64];   // xs bf16, XOR-swizzled (6 KB)

  int tid = threadIdx.x;
  int bid = blockIdx.x;
  int dir = bid / NSEQ;
  int seq = bid % NSEQ;
  int b = seq / SL, q = seq % SL;
  int pbase, pstride;
  if (dir == 0)      { pbase = (b * SL) * SL + q;           pstride = SL;  }
  else if (dir == 1) { pbase = (b * SL + SL - 1) * SL + q;  pstride = -SL; }
  else if (dir == 2) { pbase = (b * SL + q) * SL;           pstride = 1;   }
  else               { pbase = (b * SL + q) * SL + SL - 1;  pstride = -1;  }

  int wv = tid >> 6, lane = tid & 63;

  // Phase A: stage xraw rows into R1
  for (int t = wv; t < L; t += 4)
    R1[t * 64 + lane] = xraw[(pbase + t * pstride) * 64 + lane];
  __syncthreads();

  // Phase B: causal conv k=4 + silu -> R3 (f32) + R4u (bf16, swizzled)
  for (int e = tid; e < L * 64; e += 256) {
    int t = e >> 6, d = e & 63;
    float4 cw = reinterpret_cast<const float4*>(convw)[d];
    float s = convb[d] + R1[t * 64 + d] * cw.w;
    if (t >= 1) s += R1[(t - 1) * 64 + d] * cw.z;
    if (t >= 2) s += R1[(t - 2) * 64 + d] * cw.y;
    if (t >= 3) s += R1[(t - 3) * 64 + d] * cw.x;
    float xs = s / (1.f + __expf(-s));
    R3[t * 64 + d] = xs;
    R4u[t * 64 + (d ^ ((t & 7) << 3))] = f2b(xs);
  }
  __syncthreads();

  // Phase C1: delta = softplus(xs @ M^T + bdt)  (exact f32 path) -> R1
  {
    int tr = wv * 12;
    float aD[12];
    #pragma unroll
    for (int j = 0; j < 12; ++j) aD[j] = 0.f;
    const float4* pms = reinterpret_cast<const float4*>(PMs);
    for (int k4 = 0; k4 < 16; ++k4) {
      float4 wd = pms[k4 * 64 + lane];
      #pragma unroll
      for (int j = 0; j < 12; ++j) {
        float4 x4 = *reinterpret_cast<const float4*>(&R3[(tr + j) * 64 + k4 * 4]);
        aD[j] += wd.x * x4.x + wd.y * x4.y + wd.z * x4.z + wd.w * x4.w;
      }
    }
    float bdl = bdt[lane];
    #pragma unroll
    for (int j = 0; j < 12; ++j) {
      float s = aD[j] + bdl;
      s = (s > 15.f) ? s : __logf(1.f + __expf(s));
      R1[(tr + j) * 64 + lane] = s;
    }
  }

  // Phase C2: Bp|Cp = xs @ Wx[64:192]^T via bf16 MFMA -> R2u (bf16)
  {
    short8 bfrag[2][2];                          // [ntl][ks]
    const short8* pw8 = reinterpret_cast<const short8*>(PW2);
    #pragma unroll
    for (int ntl = 0; ntl < 2; ++ntl)
      #pragma unroll
      for (int ks = 0; ks < 2; ++ks)
        bfrag[ntl][ks] = pw8[((2 * wv + ntl) * 2 + ks) * 64 + lane];
    f32x4 acc[3][2];
    #pragma unroll
    for (int mt = 0; mt < 3; ++mt)
      #pragma unroll
      for (int ntl = 0; ntl < 2; ++ntl)
        acc[mt][ntl] = (f32x4){0.f, 0.f, 0.f, 0.f};
    #pragma unroll
    for (int mt = 0; mt < 3; ++mt) {
      int row = mt * 16 + (lane & 15);
      #pragma unroll
      for (int ks = 0; ks < 2; ++ks) {
        int within = (ks * 32 + ((lane >> 4) * 8)) ^ ((row & 7) << 3);
        short8 af = *reinterpret_cast<const short8*>(&R4u[row * 64 + within]);
        acc[mt][0] = __builtin_amdgcn_mfma_f32_16x16x32_bf16(af, bfrag[0][ks], acc[mt][0], 0, 0, 0);
        acc[mt][1] = __builtin_amdgcn_mfma_f32_16x16x32_bf16(af, bfrag[1][ks], acc[mt][1], 0, 0, 0);
      }
    }
    #pragma unroll
    for (int mt = 0; mt < 3; ++mt)
      #pragma unroll
      for (int ntl = 0; ntl < 2; ++ntl)
        #pragma unroll
        for (int qq = 0; qq < 4; ++qq) {
          int t = mt * 16 + (lane >> 4) * 4 + qq;
          int rr = (2 * wv + ntl) * 16 + (lane & 15);
          R2u[t * 136 + rr] = f2b(acc[mt][ntl][qq]);
        }
  }
  __syncthreads();

  // Phase D: 48-step scan. d = tid>>2, sg = tid&3 (16 states each).
  {
    int d = tid >> 2, sg = tid & 3;
    float A_[16];
    #pragma unroll
    for (int j = 0; j < 16; ++j) A_[j] = -__expf(Alog[d * 64 + sg * 16 + j]);
    float a0 = A_[0], dstep = A_[1] - A_[0];
    bool arith = true;
    #pragma unroll
    for (int j = 0; j < 16; ++j)
      arith = arith && (fabsf(A_[j] - (a0 + j * dstep)) <= 1e-3f * (1.f + fabsf(A_[j])));
    const float L2E = 1.44269504f;
    float a0L = a0 * L2E, ddL = dstep * L2E;
    float A2_[16];
    #pragma unroll
    for (int j = 0; j < 16; ++j) A2_[j] = A_[j] * L2E;
    float h[16];
    #pragma unroll
    for (int j = 0; j < 16; ++j) h[j] = 0.f;
    float Dd = Dv[d];

    for (int t = 0; t < L; ++t) {
      float dlt = R1[t * 64 + d];                        // delta (f32)
      float bb = dlt * b2f(R2u[t * 136 + d]);            // B_bar
      short8 c0 = *reinterpret_cast<const short8*>(&R2u[t * 136 + 64 + sg * 16]);
      short8 c1 = *reinterpret_cast<const short8*>(&R2u[t * 136 + 64 + sg * 16 + 8]);
      float ab[16];
      if (arith) {                                       // A arithmetic in s:
        float P = exp2f(dlt * a0L);                      // 2 exps + muls
        float Rr = exp2f(dlt * ddL);
        float R2v = Rr * Rr, R4v = R2v * R2v, R8v = R4v * R4v;
        ab[0] = P;          ab[1] = P * Rr;
        ab[2] = P * R2v;    ab[3] = ab[1] * R2v;
        #pragma unroll
        for (int j = 0; j < 4; ++j) ab[4 + j] = ab[j] * R4v;
        #pragma unroll
        for (int j = 0; j < 8; ++j) ab[8 + j] = ab[j] * R8v;
      } else {                                           // general fallback
        #pragma unroll
        for (int j = 0; j < 16; ++j) ab[j] = exp2f(dlt * A2_[j]);
      }
      float part = 0.f;
      #pragma unroll
      for (int j = 0; j < 8; ++j) {
        h[j] = ab[j] * h[j] + bb;
        part += h[j] * b2f((ushort)c0[j]);
      }
      #pragma unroll
      for (int j = 0; j < 8; ++j) {
        h[8 + j] = ab[8 + j] * h[8 + j] + bb;
        part += h[8 + j] * b2f((ushort)c1[j]);
      }
      part += __shfl_xor(part, 1);
      part += __shfl_xor(part, 2);
      if (sg == 0) R1[t * 64 + d] = part + Dd * R3[t * 64 + d];   // y + D*xs
    }
  }
  __syncthreads();

  // P6a: gate with silu(z)
  for (int e = tid; e < L * 64; e += 256) {
    int t = e >> 6, d = e & 63;
    R1[t * 64 + d] *= slz[(pbase + t * pstride) * 64 + d];
  }
  __syncthreads();

  // P6b: out-projection + atomic accumulate
  for (int e = tid; e < L * 32; e += 256) {
    int t = e >> 5, c = e & 31;
    const float4* po = reinterpret_cast<const float4*>(PO);
    const float* yv = R1 + t * 64;
    float s = 0.f;
    #pragma unroll
    for (int d4 = 0; d4 < 16; ++d4) {
      float4 w = po[d4 * 32 + c];
      const float* yp = yv + d4 * 4;
      s += w.x * yp[0] + w.y * yp[1] + w.z * yp[2] + w.w * yp[3];
    }
    atomicAdd(&out[(pbase + t * pstride) * 32 + c], s);
  }
}

extern "C" void kernel_launch(void* const* d_in, const int* in_sizes, int n_in,
                              void* d_out, int out_size, void* d_ws, size_t ws_size,
                              hipStream_t stream) {
  const float* x     = (const float*)d_in[0];
  const float* Win   = (const float*)d_in[1];
  const float* convw = (const float*)d_in[2];
  const float* convb = (const float*)d_in[3];
  const float* Wx    = (const float*)d_in[4];
  const float* Wdt   = (const float*)d_in[5];
  const float* bdt   = (const float*)d_in[6];
  const float* Alog  = (const float*)d_in[7];
  const float* Dv    = (const float*)d_in[8];
  const float* Wout  = (const float*)d_in[9];

  float* xraw = (float*)d_ws;                 // [9216][64] f32
  float* slz  = xraw + NPIX * 64;             // [9216][64] f32
  float* PMs  = slz + NPIX * 64;              // 4096 f32
  float* PO   = PMs + 4096;                   // 2048 f32
  ushort* PW2 = (ushort*)(PO + 2048);         // 8192 bf16
  float* out  = (float*)d_out;

  k_pre<<<NPREB, 256, 0, stream>>>(x, Win, Wdt, Wx, Wout, xraw, slz,
                                   PMs, PO, PW2, out);
  k_scan<<<NBLK, 256, 0, stream>>>(xraw, slz, PMs, PW2, PO, convw, convb,
                                   bdt, Alog, Dv, out);
}